// Round 2
// baseline (198.937 us; speedup 1.0000x reference)
//
#include <hip/hip_runtime.h>

// VMamba SS2D block, fp32. B=128, spatial 8x8 (L=64), DI=256, K=4 dirs, G=4 groups,
// Dg=64, N=6 state, dt-rank 6.
//
// ws layout (floats): xc2[128*64*256] | xflat_t[128*64*256] | y_t[128*4*64*256]
// z is stored in d_out (K1 writes it, K5 consumes then overwrites with final out).

#define DEV __device__ __forceinline__

DEV float fast_silu(float x) { return x / (1.f + __expf(-x)); }
DEV float fast_softplus(float x) {
    return fmaxf(x, 0.f) + __logf(1.f + __expf(-fabsf(x)));
}
DEV float dot4(float4 a, float4 b) {
    return a.x * b.x + a.y * b.y + a.z * b.z + a.w * b.w;
}

// ---------------- K1: z[b][l][e] = silu(sum_d x_in[b,l,d] * w[e,d]) ----------------
// 16 rows/block, each thread 8 rows x 2 cols.
__global__ __launch_bounds__(256) void k1_inproj(const float* __restrict__ x_in,
                                                 const float* __restrict__ w,
                                                 float* __restrict__ z) {
    __shared__ float xr[16][256];
    const int blk = blockIdx.x;              // b*4 + quarter
    const int b = blk >> 2, l0 = (blk & 3) * 16;
    const int tid = threadIdx.x;
    const float* xbase = x_in + (b * 64 + l0) * 256;
    for (int idx = tid; idx < 16 * 256; idx += 256)
        xr[idx >> 8][idx & 255] = xbase[idx];
    __syncthreads();
    const int rh = tid >> 7;                 // 0..1 -> rows rh*8..rh*8+7
    const int cp = tid & 127;
    const int e0 = cp, e1 = cp + 128;
    float acc[8][2];
#pragma unroll
    for (int p = 0; p < 8; p++) { acc[p][0] = 0.f; acc[p][1] = 0.f; }
    const float* w0 = w + e0 * 256;
    const float* w1 = w + e1 * 256;
    for (int d0 = 0; d0 < 256; d0 += 4) {
        float4 wa = *reinterpret_cast<const float4*>(w0 + d0);
        float4 wb = *reinterpret_cast<const float4*>(w1 + d0);
#pragma unroll
        for (int p = 0; p < 8; p++) {
            float4 x4 = *reinterpret_cast<const float4*>(&xr[rh * 8 + p][d0]);
            acc[p][0] += dot4(x4, wa);
            acc[p][1] += dot4(x4, wb);
        }
    }
    float* zbase = z + (b * 64 + l0) * 256;
#pragma unroll
    for (int p = 0; p < 8; p++) {
        zbase[(rh * 8 + p) * 256 + e0] = fast_silu(acc[p][0]);
        zbase[(rh * 8 + p) * 256 + e1] = fast_silu(acc[p][1]);
    }
}

// ---------------- K2: depthwise 3x3 SAME conv + bias + silu ----------------
// x_[b,c,H,W] = x_in[b, H>>3, W>>3, c*64 + (H&7)*8 + (W&7)]
// output xc2[b][i][j][c][dh][dw]  (patch-major, 256 contiguous per patch)
__global__ __launch_bounds__(256) void k2_dwconv(const float* __restrict__ x_in,
                                                 const float* __restrict__ cw,
                                                 const float* __restrict__ cb,
                                                 float* __restrict__ xc2) {
    const int blk = blockIdx.x;              // b*64 + pi*8 + pj
    const int b = blk >> 6, pi = (blk >> 3) & 7, pj = blk & 7;
    const int tid = threadIdx.x;             // c*64 + dh*8 + dw
    const int c = tid >> 6, dh = (tid >> 3) & 7, dw = tid & 7;
    const int H = pi * 8 + dh, W = pj * 8 + dw;
    float acc = cb[c];
#pragma unroll
    for (int u = 0; u < 3; u++) {
        int Hp = H + u - 1;
        if (Hp < 0 || Hp > 63) continue;
#pragma unroll
        for (int v = 0; v < 3; v++) {
            int Wp = W + v - 1;
            if (Wp < 0 || Wp > 63) continue;
            float xv = x_in[((b * 8 + (Hp >> 3)) * 8 + (Wp >> 3)) * 256 +
                            c * 64 + ((Hp & 7) << 3) + (Wp & 7)];
            acc += xv * cw[c * 9 + u * 3 + v];
        }
    }
    xc2[blk * 256 + tid] = fast_silu(acc);
}

// ---------------- K3: patch embed GEMM + bias + BN -> xflat_t[b][l][e] ----------------
__global__ __launch_bounds__(256) void k3_patch_bn(const float* __restrict__ xc2,
                                                   const float* __restrict__ pw,
                                                   const float* __restrict__ pb,
                                                   const float* __restrict__ gamma,
                                                   const float* __restrict__ beta,
                                                   const float* __restrict__ mean,
                                                   const float* __restrict__ var,
                                                   float* __restrict__ xflat_t) {
    __shared__ float xr[16][256];
    const int blk = blockIdx.x;
    const int b = blk >> 2, l0 = (blk & 3) * 16;
    const int tid = threadIdx.x;
    const float* xbase = xc2 + (b * 64 + l0) * 256;
    for (int idx = tid; idx < 16 * 256; idx += 256)
        xr[idx >> 8][idx & 255] = xbase[idx];
    __syncthreads();
    const int rh = tid >> 7;
    const int cp = tid & 127;
    const int e0 = cp, e1 = cp + 128;
    float acc[8][2];
#pragma unroll
    for (int p = 0; p < 8; p++) { acc[p][0] = 0.f; acc[p][1] = 0.f; }
    const float* w0 = pw + e0 * 256;
    const float* w1 = pw + e1 * 256;
    for (int d0 = 0; d0 < 256; d0 += 4) {
        float4 wa = *reinterpret_cast<const float4*>(w0 + d0);
        float4 wb = *reinterpret_cast<const float4*>(w1 + d0);
#pragma unroll
        for (int p = 0; p < 8; p++) {
            float4 x4 = *reinterpret_cast<const float4*>(&xr[rh * 8 + p][d0]);
            acc[p][0] += dot4(x4, wa);
            acc[p][1] += dot4(x4, wb);
        }
    }
    const float sc0 = rsqrtf(var[e0] + 1e-5f) * gamma[e0];
    const float sh0 = beta[e0] - mean[e0] * sc0;
    const float sc1 = rsqrtf(var[e1] + 1e-5f) * gamma[e1];
    const float sh1 = beta[e1] - mean[e1] * sc1;
    const float b0 = pb[e0], b1 = pb[e1];
    float* obase = xflat_t + (b * 64 + l0) * 256;
#pragma unroll
    for (int p = 0; p < 8; p++) {
        obase[(rh * 8 + p) * 256 + e0] = (acc[p][0] + b0) * sc0 + sh0;
        obase[(rh * 8 + p) * 256 + e1] = (acc[p][1] + b1) * sc1 + sh1;
    }
}

DEV int lperm(int k, int l) {
    // source index (k=0 order) for direction k, step l
    if (k == 0) return l;
    if (k == 1) return ((l & 7) << 3) | (l >> 3);
    if (k == 2) return 63 - l;
    int lf = 63 - l;
    return ((lf & 7) << 3) | (lf >> 3);
}

// ---------------- K4: per-(b,g) projection + 4-direction selective scan ----------------
// grid 512 = b*4 + g; 256 threads; wave w handles direction k=w.
// writes y_t[b][k][l][e]  (e = g*64+d contiguous)
__global__ __launch_bounds__(256) void k4_scan(const float* __restrict__ xflat_t,
                                               const float* __restrict__ xpw_g,
                                               const float* __restrict__ dt_w,
                                               const float* __restrict__ dt_b,
                                               const float* __restrict__ A_logs,
                                               const float* __restrict__ Ds,
                                               float* __restrict__ y_t) {
    __shared__ float xg[64][65];         // [d][l] in k=0 order, pad 65
    __shared__ float xpw_s[4 * 18 * 64]; // [k][c][d]
    __shared__ float xdbl_t[4][64][20];  // [k][l][c], pad 20 (16B aligned rows)
    const int blk = blockIdx.x;          // b*4 + g
    const int b = blk >> 2, g = blk & 3;
    const int tid = threadIdx.x;
    const int k = tid >> 6;              // wave -> direction
    const int lane = tid & 63;
    const int gk = g * 4 + k;

    // stage xg[d][l] = xflat_t[b, l, g*64+d]
    for (int idx = tid; idx < 4096; idx += 256) {
        int d = idx & 63, l = idx >> 6;
        xg[d][l] = xflat_t[(b * 64 + l) * 256 + g * 64 + d];
    }
    // stage x_proj_w for this g: 4608 contiguous floats
    for (int idx = tid; idx < 4 * 18 * 64; idx += 256)
        xpw_s[idx] = xpw_g[g * 4608 + idx];
    __syncthreads();

    // projection: wave k, lane l computes xdbl_t[k][l][c] for c=0..17
    {
        const int ls = lperm(k, lane);
        float xc[64];
#pragma unroll
        for (int d = 0; d < 64; d++) xc[d] = xg[d][ls];
        const float* wbase = &xpw_s[k * 1152];
        float* orow = &xdbl_t[k][lane][0];
        for (int c = 0; c < 18; c++) {
            const float4* wr = reinterpret_cast<const float4*>(wbase + c * 64);
            float s = 0.f;
#pragma unroll
            for (int d4 = 0; d4 < 16; d4++) {
                float4 w4 = wr[d4];
                s += xc[4 * d4] * w4.x + xc[4 * d4 + 1] * w4.y +
                     xc[4 * d4 + 2] * w4.z + xc[4 * d4 + 3] * w4.w;
            }
            orow[c] = s;
        }
    }
    __syncthreads();

    // scan: wave k, lane d
    {
        const int d = lane;
        float dtw[6], Av[6];
#pragma unroll
        for (int r = 0; r < 6; r++) dtw[r] = dt_w[(gk * 64 + d) * 6 + r];
#pragma unroll
        for (int n = 0; n < 6; n++) Av[n] = -__expf(A_logs[(gk * 64 + d) * 6 + n]);
        const float dtb = dt_b[gk * 64 + d];
        const float Dsv = Ds[gk * 64 + d];
        float h[6];
#pragma unroll
        for (int n = 0; n < 6; n++) h[n] = 0.f;
        float* ybase = y_t + ((size_t)(b * 4 + k) * 64) * 256 + g * 64 + d;
        for (int l = 0; l < 64; l++) {
            const float4* row = reinterpret_cast<const float4*>(&xdbl_t[k][l][0]);
            float4 q0 = row[0], q1 = row[1], q2 = row[2], q3 = row[3], q4 = row[4];
            float delta = dtb + q0.x * dtw[0] + q0.y * dtw[1] + q0.z * dtw[2] +
                          q0.w * dtw[3] + q1.x * dtw[4] + q1.y * dtw[5];
            delta = fast_softplus(delta);
            const int ls = lperm(k, l);
            float xv = xg[d][ls];
            float dxu = delta * xv;
            float Bv[6] = {q1.z, q1.w, q2.x, q2.y, q2.z, q2.w};
            float Cv[6] = {q3.x, q3.y, q3.z, q3.w, q4.x, q4.y};
            float y = 0.f;
#pragma unroll
            for (int n = 0; n < 6; n++) {
                h[n] = __expf(delta * Av[n]) * h[n] + dxu * Bv[n];
                y += h[n] * Cv[n];
            }
            ybase[l * 256] = y + Dsv * xv;
        }
    }
}

// ---------------- K5: combine 4 dirs + LayerNorm + z-gate + out_proj ----------------
__global__ __launch_bounds__(256) void k5_out(const float* __restrict__ y_t,
                                              const float* zp,            // aliases out!
                                              const float* __restrict__ lng,
                                              const float* __restrict__ lnb,
                                              const float* __restrict__ ow,
                                              float* outp) {
    __shared__ float ylr[8][256];
    __shared__ float scratch[8];
    const int blk = blockIdx.x;
    const int b = blk >> 3, l0 = (blk & 7) * 8;
    const int tid = threadIdx.x;
    const float gma = lng[tid], bta = lnb[tid];
    const float* ybase = y_t + (size_t)b * 4 * 64 * 256;
    for (int p = 0; p < 8; p++) {
        int l = l0 + p;
        int t = ((l & 7) << 3) | (l >> 3);
        float v = ybase[(0 * 64 + l) * 256 + tid]
                + ybase[(2 * 64 + (63 - l)) * 256 + tid]
                + ybase[(1 * 64 + t) * 256 + tid]
                + ybase[(3 * 64 + (63 - t)) * 256 + tid];
        float a = v, sq = v * v;
#pragma unroll
        for (int off = 32; off; off >>= 1) {
            a += __shfl_down(a, off, 64);
            sq += __shfl_down(sq, off, 64);
        }
        if ((tid & 63) == 0) { scratch[tid >> 6] = a; scratch[4 + (tid >> 6)] = sq; }
        __syncthreads();
        float mu = (scratch[0] + scratch[1] + scratch[2] + scratch[3]) * (1.f / 256.f);
        float ms = (scratch[4] + scratch[5] + scratch[6] + scratch[7]) * (1.f / 256.f);
        float inv = rsqrtf(ms - mu * mu + 1e-5f);
        float yn = (v - mu) * inv * gma + bta;
        ylr[p][tid] = yn * zp[(b * 64 + l) * 256 + tid];
        __syncthreads();
    }
    const int rh = tid >> 7;                 // rows rh*4 .. rh*4+3
    const int cp = tid & 127;
    const int e0 = cp, e1 = cp + 128;
    float acc[4][2];
#pragma unroll
    for (int p = 0; p < 4; p++) { acc[p][0] = 0.f; acc[p][1] = 0.f; }
    const float* w0 = ow + e0 * 256;
    const float* w1 = ow + e1 * 256;
    for (int d0 = 0; d0 < 256; d0 += 4) {
        float4 wa = *reinterpret_cast<const float4*>(w0 + d0);
        float4 wb = *reinterpret_cast<const float4*>(w1 + d0);
#pragma unroll
        for (int p = 0; p < 4; p++) {
            float4 x4 = *reinterpret_cast<const float4*>(&ylr[rh * 4 + p][d0]);
            acc[p][0] += dot4(x4, wa);
            acc[p][1] += dot4(x4, wb);
        }
    }
    float* obase = outp + (b * 64 + l0) * 256;
#pragma unroll
    for (int p = 0; p < 4; p++) {
        obase[(rh * 4 + p) * 256 + e0] = acc[p][0];
        obase[(rh * 4 + p) * 256 + e1] = acc[p][1];
    }
}

extern "C" void kernel_launch(void* const* d_in, const int* in_sizes, int n_in,
                              void* d_out, int out_size, void* d_ws, size_t ws_size,
                              hipStream_t stream) {
    (void)in_sizes; (void)n_in; (void)out_size; (void)ws_size;
    const float* x_in      = (const float*)d_in[0];
    const float* in_proj_w = (const float*)d_in[1];
    const float* conv_w    = (const float*)d_in[2];
    const float* conv_b    = (const float*)d_in[3];
    const float* patch_w   = (const float*)d_in[4];
    const float* patch_b   = (const float*)d_in[5];
    const float* bn_gamma  = (const float*)d_in[6];
    const float* bn_beta   = (const float*)d_in[7];
    const float* bn_mean   = (const float*)d_in[8];
    const float* bn_var    = (const float*)d_in[9];
    const float* x_proj_w  = (const float*)d_in[10];
    const float* dt_w      = (const float*)d_in[11];
    const float* dt_b      = (const float*)d_in[12];
    const float* A_logs    = (const float*)d_in[13];
    const float* Ds        = (const float*)d_in[14];
    const float* ln_gamma  = (const float*)d_in[15];
    const float* ln_beta   = (const float*)d_in[16];
    const float* out_proj_w= (const float*)d_in[17];

    float* out = (float*)d_out;
    float* ws  = (float*)d_ws;
    float* xc2     = ws;                 // 2,097,152 floats
    float* xflat_t = ws + 2097152;       // 2,097,152 floats
    float* y_t     = ws + 4194304;       // 8,388,608 floats
    float* z = out;                      // d_out doubles as z scratch

    hipLaunchKernelGGL(k1_inproj, dim3(512), dim3(256), 0, stream, x_in, in_proj_w, z);
    hipLaunchKernelGGL(k2_dwconv, dim3(8192), dim3(256), 0, stream, x_in, conv_w, conv_b, xc2);
    hipLaunchKernelGGL(k3_patch_bn, dim3(512), dim3(256), 0, stream,
                       xc2, patch_w, patch_b, bn_gamma, bn_beta, bn_mean, bn_var, xflat_t);
    hipLaunchKernelGGL(k4_scan, dim3(512), dim3(256), 0, stream,
                       xflat_t, x_proj_w, dt_w, dt_b, A_logs, Ds, y_t);
    hipLaunchKernelGGL(k5_out, dim3(1024), dim3(256), 0, stream,
                       y_t, z, ln_gamma, ln_beta, out_proj_w, out);
}

// Round 3
// 111.893 us; speedup vs baseline: 1.7779x; 1.7779x over previous
//
#include <hip/hip_runtime.h>

// VMamba SS2D block. B=128, spatial 8x8 (L=64), DI=256, K=4 dirs, G=4 groups,
// Dg=64, N=6 state, dt-rank 6.
//
// Pipeline: K0 convert weights->bf16 | K1 in_proj MFMA (+silu) -> z (in d_out)
// K2 dwconv+silu -> bf16 patches | K3 patch MFMA + BN -> xflat_t fp32
// K4 proj+4-dir scan -> y_t fp32 | K4b combine+LN+gate -> yl bf16
// K5 out_proj MFMA -> d_out fp32.
//
// ws (bytes): y_t fp32 33,554,432 | xflat_t fp32 8,388,608 |
//             regA bf16 4,194,304 (xc2 bf16, later reused as yl bf16) |
//             w_bf16 3x131,072. Total 46,530,560.

typedef __attribute__((ext_vector_type(8))) short bf16x8;
typedef __attribute__((ext_vector_type(4))) short short4v;
typedef __attribute__((ext_vector_type(4))) float f32x4;

#define DEV __device__ __forceinline__

DEV float fast_silu(float x) { return x / (1.f + __expf(-x)); }
DEV float fast_softplus(float x) {
    return fmaxf(x, 0.f) + __logf(1.f + __expf(-fabsf(x)));
}
DEV short f2bf(float f) {            // RNE float->bf16
    unsigned u = __builtin_bit_cast(unsigned, f);
    u += 0x7fff + ((u >> 16) & 1);
    return (short)(u >> 16);
}

// ---------------- K0: convert the three 256x256 weight matrices to bf16 ----------------
__global__ __launch_bounds__(256) void k0_convert(const float* __restrict__ w1,
                                                  const float* __restrict__ w3,
                                                  const float* __restrict__ w5,
                                                  short* __restrict__ o1,
                                                  short* __restrict__ o3,
                                                  short* __restrict__ o5) {
    int t = blockIdx.x * 256 + threadIdx.x;      // 0..49151
    int which = t >> 14;
    int i = (t & 16383) << 2;
    const float* s = which == 0 ? w1 : (which == 1 ? w3 : w5);
    short* o = which == 0 ? o1 : (which == 1 ? o3 : o5);
    float4 v = *reinterpret_cast<const float4*>(s + i);
    short4v r;
    r[0] = f2bf(v.x); r[1] = f2bf(v.y); r[2] = f2bf(v.z); r[3] = f2bf(v.w);
    *reinterpret_cast<short4v*>(o + i) = r;
}

// ---------------- K1: z = silu(x_in @ in_proj_w^T), MFMA, A fp32 ----------------
// grid 512: 16 rows/block, 4 waves x 64 cols.
__global__ __launch_bounds__(256) void k1_inproj_mfma(const float* __restrict__ A,
                                                      const short* __restrict__ W,
                                                      float* __restrict__ out) {
    const int m0 = blockIdx.x * 16;
    const int tid = threadIdx.x;
    const int wave = tid >> 6, lane = tid & 63;
    const int r16 = lane & 15, kch = lane >> 4;
    const int ec0 = wave * 64;
    f32x4 acc[4] = {};
    const float* pa = A + (m0 + r16) * 256 + kch * 8;
#pragma unroll
    for (int d0 = 0; d0 < 256; d0 += 32) {
        bf16x8 a;
        {
            float4 lo = *reinterpret_cast<const float4*>(pa + d0);
            float4 hi = *reinterpret_cast<const float4*>(pa + d0 + 4);
            a[0] = f2bf(lo.x); a[1] = f2bf(lo.y); a[2] = f2bf(lo.z); a[3] = f2bf(lo.w);
            a[4] = f2bf(hi.x); a[5] = f2bf(hi.y); a[6] = f2bf(hi.z); a[7] = f2bf(hi.w);
        }
#pragma unroll
        for (int c = 0; c < 4; c++) {
            bf16x8 b = *reinterpret_cast<const bf16x8*>(
                W + (ec0 + c * 16 + r16) * 256 + d0 + kch * 8);
            acc[c] = __builtin_amdgcn_mfma_f32_16x16x32_bf16(a, b, acc[c], 0, 0, 0);
        }
    }
#pragma unroll
    for (int c = 0; c < 4; c++) {
        float* po = out + (m0 + kch * 4) * 256 + ec0 + c * 16 + r16;
#pragma unroll
        for (int j = 0; j < 4; j++) po[j * 256] = fast_silu(acc[c][j]);
    }
}

// ---------------- K2: depthwise 3x3 SAME conv + bias + silu -> bf16 patches ----------------
__global__ __launch_bounds__(256) void k2_dwconv(const float* __restrict__ x_in,
                                                 const float* __restrict__ cw,
                                                 const float* __restrict__ cb,
                                                 short* __restrict__ xc2b) {
    const int blk = blockIdx.x;              // b*64 + pi*8 + pj
    const int b = blk >> 6, pi = (blk >> 3) & 7, pj = blk & 7;
    const int tid = threadIdx.x;             // c*64 + dh*8 + dw
    const int c = tid >> 6, dh = (tid >> 3) & 7, dw = tid & 7;
    const int H = pi * 8 + dh, W = pj * 8 + dw;
    float acc = cb[c];
#pragma unroll
    for (int u = 0; u < 3; u++) {
        int Hp = H + u - 1;
        if (Hp < 0 || Hp > 63) continue;
#pragma unroll
        for (int v = 0; v < 3; v++) {
            int Wp = W + v - 1;
            if (Wp < 0 || Wp > 63) continue;
            float xv = x_in[((b * 8 + (Hp >> 3)) * 8 + (Wp >> 3)) * 256 +
                            c * 64 + ((Hp & 7) << 3) + (Wp & 7)];
            acc += xv * cw[c * 9 + u * 3 + v];
        }
    }
    xc2b[blk * 256 + tid] = f2bf(fast_silu(acc));
}

// ---------------- K3: patch embed MFMA + bias + BN -> xflat_t fp32 ----------------
__global__ __launch_bounds__(256) void k3_patch_mfma(const short* __restrict__ A,
                                                     const short* __restrict__ W,
                                                     const float* __restrict__ pb,
                                                     const float* __restrict__ gamma,
                                                     const float* __restrict__ beta,
                                                     const float* __restrict__ mean,
                                                     const float* __restrict__ var,
                                                     float* __restrict__ out) {
    const int m0 = blockIdx.x * 16;
    const int tid = threadIdx.x;
    const int wave = tid >> 6, lane = tid & 63;
    const int r16 = lane & 15, kch = lane >> 4;
    const int ec0 = wave * 64;
    f32x4 acc[4] = {};
    const short* pa = A + (m0 + r16) * 256 + kch * 8;
#pragma unroll
    for (int d0 = 0; d0 < 256; d0 += 32) {
        bf16x8 a = *reinterpret_cast<const bf16x8*>(pa + d0);
#pragma unroll
        for (int c = 0; c < 4; c++) {
            bf16x8 b = *reinterpret_cast<const bf16x8*>(
                W + (ec0 + c * 16 + r16) * 256 + d0 + kch * 8);
            acc[c] = __builtin_amdgcn_mfma_f32_16x16x32_bf16(a, b, acc[c], 0, 0, 0);
        }
    }
#pragma unroll
    for (int c = 0; c < 4; c++) {
        const int e = ec0 + c * 16 + r16;
        const float sc = rsqrtf(var[e] + 1e-5f) * gamma[e];
        const float sh = beta[e] - mean[e] * sc;
        const float bias = pb[e];
        float* po = out + (m0 + kch * 4) * 256 + e;
#pragma unroll
        for (int j = 0; j < 4; j++) po[j * 256] = (acc[c][j] + bias) * sc + sh;
    }
}

DEV int lperm(int k, int l) {
    if (k == 0) return l;
    if (k == 1) return ((l & 7) << 3) | (l >> 3);
    if (k == 2) return 63 - l;
    int lf = 63 - l;
    return ((lf & 7) << 3) | (lf >> 3);
}

// ---------------- K4: per-(b,g) projection + 4-direction selective scan ----------------
__global__ __launch_bounds__(256) void k4_scan(const float* __restrict__ xflat_t,
                                               const float* __restrict__ xpw_g,
                                               const float* __restrict__ dt_w,
                                               const float* __restrict__ dt_b,
                                               const float* __restrict__ A_logs,
                                               const float* __restrict__ Ds,
                                               float* __restrict__ y_t) {
    __shared__ float xg[64][65];         // [d][l] in k=0 order
    __shared__ float xpw_s[4 * 18 * 64]; // [k][c][d]
    __shared__ float xdbl_t[4][64][20];  // [k][l][c]
    const int blk = blockIdx.x;          // b*4 + g
    const int b = blk >> 2, g = blk & 3;
    const int tid = threadIdx.x;
    const int k = tid >> 6;
    const int lane = tid & 63;
    const int gk = g * 4 + k;

    for (int idx = tid; idx < 4096; idx += 256) {
        int d = idx & 63, l = idx >> 6;
        xg[d][l] = xflat_t[(b * 64 + l) * 256 + g * 64 + d];
    }
    for (int idx = tid; idx < 4 * 18 * 64; idx += 256)
        xpw_s[idx] = xpw_g[g * 4608 + idx];
    __syncthreads();

    {
        const int ls = lperm(k, lane);
        float xc[64];
#pragma unroll
        for (int d = 0; d < 64; d++) xc[d] = xg[d][ls];
        const float* wbase = &xpw_s[k * 1152];
        float* orow = &xdbl_t[k][lane][0];
        for (int c = 0; c < 18; c++) {
            const float4* wr = reinterpret_cast<const float4*>(wbase + c * 64);
            float s = 0.f;
#pragma unroll
            for (int d4 = 0; d4 < 16; d4++) {
                float4 w4 = wr[d4];
                s += xc[4 * d4] * w4.x + xc[4 * d4 + 1] * w4.y +
                     xc[4 * d4 + 2] * w4.z + xc[4 * d4 + 3] * w4.w;
            }
            orow[c] = s;
        }
    }
    __syncthreads();

    {
        const int d = lane;
        float dtw[6], Av[6];
#pragma unroll
        for (int r = 0; r < 6; r++) dtw[r] = dt_w[(gk * 64 + d) * 6 + r];
#pragma unroll
        for (int n = 0; n < 6; n++) Av[n] = -__expf(A_logs[(gk * 64 + d) * 6 + n]);
        const float dtb = dt_b[gk * 64 + d];
        const float Dsv = Ds[gk * 64 + d];
        float h[6];
#pragma unroll
        for (int n = 0; n < 6; n++) h[n] = 0.f;
        float* ybase = y_t + ((size_t)(b * 4 + k) * 64) * 256 + g * 64 + d;
        for (int l = 0; l < 64; l++) {
            const float4* row = reinterpret_cast<const float4*>(&xdbl_t[k][l][0]);
            float4 q0 = row[0], q1 = row[1], q2 = row[2], q3 = row[3], q4 = row[4];
            float delta = dtb + q0.x * dtw[0] + q0.y * dtw[1] + q0.z * dtw[2] +
                          q0.w * dtw[3] + q1.x * dtw[4] + q1.y * dtw[5];
            delta = fast_softplus(delta);
            const int ls = lperm(k, l);
            float xv = xg[d][ls];
            float dxu = delta * xv;
            float Bv[6] = {q1.z, q1.w, q2.x, q2.y, q2.z, q2.w};
            float Cv[6] = {q3.x, q3.y, q3.z, q3.w, q4.x, q4.y};
            float y = 0.f;
#pragma unroll
            for (int n = 0; n < 6; n++) {
                h[n] = __expf(delta * Av[n]) * h[n] + dxu * Bv[n];
                y += h[n] * Cv[n];
            }
            ybase[l * 256] = y + Dsv * xv;
        }
    }
}

// ---------------- K4b: combine 4 dirs + LayerNorm + z-gate -> yl bf16 ----------------
// one wave per output row; no LDS, no barriers. grid 2048 = b*16 + lq, wave = row in lq.
__global__ __launch_bounds__(256) void k4b_combine_ln(const float* __restrict__ y_t,
                                                      const float* __restrict__ zp,
                                                      const float* __restrict__ lng,
                                                      const float* __restrict__ lnb,
                                                      short* __restrict__ yl) {
    const int blk = blockIdx.x;
    const int b = blk >> 4;
    const int wave = threadIdx.x >> 6, lane = threadIdx.x & 63;
    const int l = (blk & 15) * 4 + wave;
    const int t = ((l & 7) << 3) | (l >> 3);
    const int e0 = lane * 4;
    const float* yb = y_t + (size_t)b * 4 * 64 * 256 + e0;
    float4 v0 = *reinterpret_cast<const float4*>(yb + (0 * 64 + l) * 256);
    float4 v2 = *reinterpret_cast<const float4*>(yb + (2 * 64 + (63 - l)) * 256);
    float4 v1 = *reinterpret_cast<const float4*>(yb + (1 * 64 + t) * 256);
    float4 v3 = *reinterpret_cast<const float4*>(yb + (3 * 64 + (63 - t)) * 256);
    float4 v;
    v.x = v0.x + v1.x + v2.x + v3.x;
    v.y = v0.y + v1.y + v2.y + v3.y;
    v.z = v0.z + v1.z + v2.z + v3.z;
    v.w = v0.w + v1.w + v2.w + v3.w;
    float s = v.x + v.y + v.z + v.w;
    float sq = v.x * v.x + v.y * v.y + v.z * v.z + v.w * v.w;
#pragma unroll
    for (int off = 1; off < 64; off <<= 1) {
        s += __shfl_xor(s, off, 64);
        sq += __shfl_xor(sq, off, 64);
    }
    const float mu = s * (1.f / 256.f);
    const float inv = rsqrtf(sq * (1.f / 256.f) - mu * mu + 1e-5f);
    float4 g = *reinterpret_cast<const float4*>(lng + e0);
    float4 bt = *reinterpret_cast<const float4*>(lnb + e0);
    float4 z4 = *reinterpret_cast<const float4*>(zp + (b * 64 + l) * 256 + e0);
    short4v o;
    o[0] = f2bf(((v.x - mu) * inv * g.x + bt.x) * z4.x);
    o[1] = f2bf(((v.y - mu) * inv * g.y + bt.y) * z4.y);
    o[2] = f2bf(((v.z - mu) * inv * g.z + bt.z) * z4.z);
    o[3] = f2bf(((v.w - mu) * inv * g.w + bt.w) * z4.w);
    *reinterpret_cast<short4v*>(yl + (b * 64 + l) * 256 + e0) = o;
}

// ---------------- K5: out = yl @ out_proj_w^T, MFMA, A bf16, no epilogue ----------------
__global__ __launch_bounds__(256) void k5_out_mfma(const short* __restrict__ A,
                                                   const short* __restrict__ W,
                                                   float* __restrict__ out) {
    const int m0 = blockIdx.x * 16;
    const int tid = threadIdx.x;
    const int wave = tid >> 6, lane = tid & 63;
    const int r16 = lane & 15, kch = lane >> 4;
    const int ec0 = wave * 64;
    f32x4 acc[4] = {};
    const short* pa = A + (m0 + r16) * 256 + kch * 8;
#pragma unroll
    for (int d0 = 0; d0 < 256; d0 += 32) {
        bf16x8 a = *reinterpret_cast<const bf16x8*>(pa + d0);
#pragma unroll
        for (int c = 0; c < 4; c++) {
            bf16x8 b = *reinterpret_cast<const bf16x8*>(
                W + (ec0 + c * 16 + r16) * 256 + d0 + kch * 8);
            acc[c] = __builtin_amdgcn_mfma_f32_16x16x32_bf16(a, b, acc[c], 0, 0, 0);
        }
    }
#pragma unroll
    for (int c = 0; c < 4; c++) {
        float* po = out + (m0 + kch * 4) * 256 + ec0 + c * 16 + r16;
#pragma unroll
        for (int j = 0; j < 4; j++) po[j * 256] = acc[c][j];
    }
}

extern "C" void kernel_launch(void* const* d_in, const int* in_sizes, int n_in,
                              void* d_out, int out_size, void* d_ws, size_t ws_size,
                              hipStream_t stream) {
    (void)in_sizes; (void)n_in; (void)out_size; (void)ws_size;
    const float* x_in      = (const float*)d_in[0];
    const float* in_proj_w = (const float*)d_in[1];
    const float* conv_w    = (const float*)d_in[2];
    const float* conv_b    = (const float*)d_in[3];
    const float* patch_w   = (const float*)d_in[4];
    const float* patch_b   = (const float*)d_in[5];
    const float* bn_gamma  = (const float*)d_in[6];
    const float* bn_beta   = (const float*)d_in[7];
    const float* bn_mean   = (const float*)d_in[8];
    const float* bn_var    = (const float*)d_in[9];
    const float* x_proj_w  = (const float*)d_in[10];
    const float* dt_w      = (const float*)d_in[11];
    const float* dt_b      = (const float*)d_in[12];
    const float* A_logs    = (const float*)d_in[13];
    const float* Ds        = (const float*)d_in[14];
    const float* ln_gamma  = (const float*)d_in[15];
    const float* ln_beta   = (const float*)d_in[16];
    const float* out_proj_w= (const float*)d_in[17];

    float* out = (float*)d_out;
    float* ws  = (float*)d_ws;
    float* y_t     = ws;                          // 8,388,608 floats
    float* xflat_t = ws + 8388608;                // 2,097,152 floats
    short* regA    = (short*)(ws + 10485760);     // 2,097,152 bf16 (xc2b, then yl)
    short* w1b     = regA + 2097152;
    short* w3b     = w1b + 65536;
    short* w5b     = w3b + 65536;
    float* z = out;                               // d_out doubles as z scratch

    hipLaunchKernelGGL(k0_convert, dim3(192), dim3(256), 0, stream,
                       in_proj_w, patch_w, out_proj_w, w1b, w3b, w5b);
    hipLaunchKernelGGL(k1_inproj_mfma, dim3(512), dim3(256), 0, stream, x_in, w1b, z);
    hipLaunchKernelGGL(k2_dwconv, dim3(8192), dim3(256), 0, stream,
                       x_in, conv_w, conv_b, regA);
    hipLaunchKernelGGL(k3_patch_mfma, dim3(512), dim3(256), 0, stream,
                       regA, w3b, patch_b, bn_gamma, bn_beta, bn_mean, bn_var, xflat_t);
    hipLaunchKernelGGL(k4_scan, dim3(512), dim3(256), 0, stream,
                       xflat_t, x_proj_w, dt_w, dt_b, A_logs, Ds, y_t);
    hipLaunchKernelGGL(k4b_combine_ln, dim3(2048), dim3(256), 0, stream,
                       y_t, z, ln_gamma, ln_beta, regA);
    hipLaunchKernelGGL(k5_out_mfma, dim3(512), dim3(256), 0, stream, regA, w5b, out);
}